// Round 8
// baseline (333.987 us; speedup 1.0000x reference)
//
#include <hip/hip_runtime.h>

#define DEVI __device__ __forceinline__

typedef __attribute__((ext_vector_type(8))) __bf16 bf16x8;
typedef __attribute__((ext_vector_type(4))) float f32x4;
typedef __attribute__((ext_vector_type(4))) unsigned short u16x4;
typedef __attribute__((ext_vector_type(8))) unsigned short u16x8;

static DEVI unsigned short f2bf(float f) {  // manual RNE (cold paths)
  unsigned int i = __float_as_uint(f);
  i += 0x7fffu + ((i >> 16) & 1u);
  return (unsigned short)(i >> 16);
}

static DEVI unsigned short f2bfh(float f) {  // native cvt
  union { __bf16 h; unsigned short u; } c;
  c.h = (__bf16)f;
  return c.u;
}

static DEVI float bf2f(unsigned short u) {
  return __uint_as_float((unsigned int)u << 16);
}

static DEVI f32x4 mfma16x16x32(bf16x8 a, bf16x8 b, f32x4 c) {
  return __builtin_amdgcn_mfma_f32_16x16x32_bf16(a, b, c, 0, 0, 0);
}

static DEVI void async_ld16(const void* g, void* lds) {
  __builtin_amdgcn_global_load_lds(
      (const __attribute__((address_space(1))) void*)g,
      (__attribute__((address_space(3))) void*)lds, 16, 0, 0);
}

// ---------------- GEMM core v3: BK=64 via two BK=32 half-buffers ----------
// Each half keeps the proven m97 unpadded 64B-row layout (R6 post-mortem:
// widening rows to 128B + parity swizzle caused 9.4M conflicts). All 8
// asyncs (both halves) are issued before one barrier pair, so the
// vmcnt(0)+s_barrier drain is paid once per 32 MFMAs instead of per 16.
// OUT_MODE: 0 fp32+bias; 1 bf16+bias(+RELU); 2 QKV scatter (K scaled+swizzled,
//           Q/V plain coalesced); 3 bf16 raw (split-K partial).
template <int BN, int OUT_MODE, bool RELU>
static DEVI void gemm_bt_core(const unsigned short* __restrict__ A, int lda,
                              const unsigned short* __restrict__ Bt, int ldb,
                              int K, int m0, int n0,
                              const float* __restrict__ bias,
                              void* __restrict__ Cp, int ldc,
                              const float* __restrict__ bq,
                              const float* __restrict__ bk,
                              const float* __restrict__ bv,
                              unsigned short* __restrict__ qo,
                              unsigned short* __restrict__ ko,
                              unsigned short* __restrict__ vo) {
  constexpr int MT = (BN == 128) ? 4 : 2;
  constexpr int NT = 4;
  __shared__ __align__(16) unsigned short As[2][128 * 32];
  __shared__ __align__(16) unsigned short Bs[2][BN * 32];

  const int tid = threadIdx.x;
  const int w = tid >> 6, l = tid & 63;
  const int lr = l & 15, lq = l >> 4;
  const int wm0 = (BN == 128) ? ((w >> 1) * 64) : (w * 32);
  const int wn0 = (BN == 128) ? ((w & 1) * 64) : 0;
  const int lrow = l >> 2;
  const int lcol = (l & 3) * 8;

  f32x4 acc[MT][NT];
#pragma unroll
  for (int i = 0; i < MT; ++i)
#pragma unroll
    for (int j = 0; j < NT; ++j) acc[i][j] = (f32x4){0.f, 0.f, 0.f, 0.f};

  for (int kb = 0; kb < K; kb += 64) {
#pragma unroll
    for (int hf = 0; hf < 2; ++hf) {
      const int kh = kb + hf * 32;
#pragma unroll
      for (int p = 0; p < 2; ++p) {
        const int r0 = p * 64 + w * 16;
        async_ld16(A + (size_t)(m0 + r0 + lrow) * lda + kh + lcol,
                   As[hf] + r0 * 32);
      }
#pragma unroll
      for (int p = 0; p < BN / 64; ++p) {
        const int r0 = p * 64 + w * 16;
        async_ld16(Bt + (size_t)(n0 + r0 + lrow) * ldb + kh + lcol,
                   Bs[hf] + r0 * 32);
      }
    }
    __syncthreads();

#pragma unroll
    for (int hf = 0; hf < 2; ++hf) {
      bf16x8 af[MT], bfr[NT];
#pragma unroll
      for (int mt = 0; mt < MT; ++mt)
        af[mt] = *(const bf16x8*)(As[hf] + (wm0 + mt * 16 + lr) * 32 + lq * 8);
#pragma unroll
      for (int nt = 0; nt < NT; ++nt)
        bfr[nt] = *(const bf16x8*)(Bs[hf] + (wn0 + nt * 16 + lr) * 32 + lq * 8);
#pragma unroll
      for (int mt = 0; mt < MT; ++mt)
#pragma unroll
        for (int nt = 0; nt < NT; ++nt)
          acc[mt][nt] = mfma16x16x32(af[mt], bfr[nt], acc[mt][nt]);
    }
    __syncthreads();
  }

#pragma unroll
  for (int mt = 0; mt < MT; ++mt) {
    const int grow = m0 + wm0 + mt * 16 + lq * 4;
#pragma unroll
    for (int nt = 0; nt < NT; ++nt) {
      const int gcol = n0 + wn0 + nt * 16 + lr;
      if (OUT_MODE == 2) {
        const int which = gcol >> 10;
        const int h = (gcol >> 6) & 15;
        const int e = gcol & 63;
        const float* bp = (which == 0) ? bq : (which == 1) ? bk : bv;
        const float bvv = bp[gcol & 1023];
        unsigned short* op = (which == 0) ? qo : (which == 1) ? ko : vo;
#pragma unroll
        for (int r = 0; r < 4; ++r) {
          const int row = grow + r;
          const int b_ = row >> 11, s_ = row & 2047;
          const size_t base = (size_t)((b_ << 4) + h) * 131072 + (size_t)s_ * 64;
          if (which == 1) {
            // K: fold softmax scale (1/8 * log2e) + XOR-octet swizzle for
            // conflict-free unpadded LDS reads in k_attn.
            const int o = e >> 3;
            const int pos = (((o ^ (s_ & 7)) << 3) | (e & 7));
            op[base + pos] = f2bf((acc[mt][nt][r] + bvv) * 0.18033688011112f);
          } else {
            op[base + e] = f2bf(acc[mt][nt][r] + bvv);
          }
        }
      } else if (OUT_MODE == 3) {
#pragma unroll
        for (int r = 0; r < 4; ++r)
          ((unsigned short*)Cp)[(size_t)(grow + r) * ldc + gcol] =
              f2bf(acc[mt][nt][r]);
      } else {
        const float bvv = bias[gcol];
#pragma unroll
        for (int r = 0; r < 4; ++r) {
          float val = acc[mt][nt][r] + bvv;
          if (RELU) val = fmaxf(val, 0.f);
          if (OUT_MODE == 1)
            ((unsigned short*)Cp)[(size_t)(grow + r) * ldc + gcol] = f2bf(val);
          else
            ((float*)Cp)[(size_t)(grow + r) * ldc + gcol] = val;
        }
      }
    }
  }
}

__global__ __launch_bounds__(256) void k_gemm_qkv(
    const unsigned short* __restrict__ xb, const unsigned short* __restrict__ Wt,
    const float* __restrict__ bq, const float* __restrict__ bk,
    const float* __restrict__ bv, unsigned short* __restrict__ qo,
    unsigned short* __restrict__ ko, unsigned short* __restrict__ vo) {
  gemm_bt_core<128, 2, false>(xb, 1024, Wt, 1024, 1024, blockIdx.x * 128,
                              blockIdx.y * 128, nullptr, nullptr, 0, bq, bk, bv,
                              qo, ko, vo);
}

__global__ __launch_bounds__(256) void k_ffn1(
    const unsigned short* __restrict__ h1b, const unsigned short* __restrict__ W1t,
    const float* __restrict__ b1, unsigned short* __restrict__ f1) {
  gemm_bt_core<128, 1, true>(h1b, 1024, W1t, 1024, 1024, blockIdx.x * 128,
                             blockIdx.y * 128, b1, f1, 4096, nullptr, nullptr,
                             nullptr, nullptr, nullptr, nullptr);
}

// split-K=4, BN=128: z covers k in [z*1024, z*1024+1024); partials contiguous
// at pbase + z*4M elements. 1024 blocks -> 4 blocks/CU, 32 MFMA/wave/iter.
__global__ __launch_bounds__(256) void k_ffn2(
    const unsigned short* __restrict__ f1, const unsigned short* __restrict__ W2t,
    unsigned short* __restrict__ pbase) {
  const int z = blockIdx.z;
  unsigned short* p = pbase + (size_t)z * 4194304;
  gemm_bt_core<128, 3, false>(f1 + z * 1024, 4096, W2t + z * 1024, 4096, 1024,
                              blockIdx.x * 128, blockIdx.y * 128, nullptr, p,
                              1024, nullptr, nullptr, nullptr, nullptr, nullptr,
                              nullptr);
}

// ---------------- prep kernels ----------------
__global__ __launch_bounds__(256) void k_cvt(const float* __restrict__ src,
                                             unsigned short* __restrict__ dst) {
  const size_t i = ((size_t)blockIdx.x * 256 + threadIdx.x) * 4;
  f32x4 v = *(const f32x4*)(src + i);
  u16x4 pk;
#pragma unroll
  for (int j = 0; j < 4; ++j) pk[j] = f2bf(v[j]);
  *(u16x4*)(dst + i) = pk;
}

static DEVI void tr64(const float* __restrict__ s, int sld,
                      unsigned short* __restrict__ d, int dld) {
  __shared__ float t[64][65];
  const int tr = threadIdx.x >> 4;
  const int tc4 = (threadIdx.x & 15) * 4;
#pragma unroll
  for (int i = 0; i < 4; ++i) {
    f32x4 v = *(const f32x4*)(s + (size_t)(i * 16 + tr) * sld + tc4);
#pragma unroll
    for (int j = 0; j < 4; ++j) t[i * 16 + tr][tc4 + j] = v[j];
  }
  __syncthreads();
#pragma unroll
  for (int i = 0; i < 4; ++i) {
    const int c = i * 16 + tr;
    u16x4 pk;
#pragma unroll
    for (int j = 0; j < 4; ++j) pk[j] = f2bf(t[tc4 + j][c]);
    *(u16x4*)(d + (size_t)c * dld + tc4) = pk;
  }
}

// All three weight transposes in one launch (flat grid, 2816 blocks):
//   [0,768)      Wq/Wk/Wv [H][1024][64] -> wqkvt [3072][1024]
//   [768,1792)   W1 [1024][4096]        -> w1t   [4096][1024]
//   [1792,2816)  W2 [4096][1024]        -> w2t   [1024][4096]
__global__ __launch_bounds__(256) void k_twall(
    const float* __restrict__ Wq, const float* __restrict__ Wk,
    const float* __restrict__ Wv, const float* __restrict__ W1,
    const float* __restrict__ W2, unsigned short* __restrict__ wqkvt,
    unsigned short* __restrict__ w1t, unsigned short* __restrict__ w2t) {
  const int bid = blockIdx.x;
  if (bid < 768) {
    const int bx = bid & 15, by = bid >> 4;       // by: 0..47
    const int which = by >> 4, h = by & 15;
    const float* W = (which == 0) ? Wq : (which == 1) ? Wk : Wv;
    const float* s = W + (size_t)h * 65536;
    unsigned short* d = wqkvt + (size_t)(which * 1024 + h * 64) * 1024;
    const int r0 = bx * 64;
    tr64(s + (size_t)r0 * 64, 64, d + r0, 1024);
  } else if (bid < 1792) {
    const int t = bid - 768;
    const int bx = t & 15, by = t >> 4;           // R=1024, C=4096
    const int r0 = bx * 64, c0 = by * 64;
    tr64(W1 + (size_t)r0 * 4096 + c0, 4096, w1t + (size_t)c0 * 1024 + r0, 1024);
  } else {
    const int t = bid - 1792;
    const int bx = t & 63, by = t >> 6;           // R=4096, C=1024
    const int r0 = bx * 64, c0 = by * 64;
    tr64(W2 + (size_t)r0 * 1024 + c0, 1024, w2t + (size_t)c0 * 4096 + r0, 4096);
  }
}

// V [bh][s][dh] -> Vp [bh][dh][2048] with per-64-key kappa permutation
// (kappa = (key%16)*4 + key/16) and XOR-octet swizzle within each 128B chunk.
__global__ __launch_bounds__(256) void k_vprep(const unsigned short* __restrict__ vb,
                                               unsigned short* __restrict__ vp) {
  const int bh = blockIdx.y, t = blockIdx.x;
  __shared__ unsigned short tl[64][72];
  const int tid = threadIdx.x;
  const size_t base = (size_t)bh * 131072;
  const int kr = tid >> 3, oc = tid & 7;
#pragma unroll
  for (int p = 0; p < 2; ++p) {
    const int key = p * 32 + kr;
    *(u16x8*)&tl[key][oc * 8] =
        *(const u16x8*)(vb + base + (size_t)(t * 64 + key) * 64 + oc * 8);
  }
  __syncthreads();
#pragma unroll
  for (int p = 0; p < 2; ++p) {
    const int dh = p * 32 + kr;
    const int ok = oc ^ (dh & 7);  // kappa-octet stored at position oc
    u16x8 pk;
#pragma unroll
    for (int j = 0; j < 8; ++j) {
      const int kap = ok * 8 + j;
      const int key = (kap & 3) * 16 + (kap >> 2);
      pk[j] = tl[key][dh];
    }
    *(u16x8*)(vp + base + (size_t)dh * 2048 + t * 64 + oc * 8) = pk;
  }
}

// ---------------- flash attention (unmasked per reference bug) -------------
// No-max softmax (|score*scale| < ~4, exp2-safe). Scale pre-folded into K.
// 512 threads / 8 waves, 16 Q-rows per wave; async dbuf staging, 1 barrier.
__global__ __launch_bounds__(512) void k_attn(
    const unsigned short* __restrict__ q, const unsigned short* __restrict__ ks,
    const unsigned short* __restrict__ vp, float* __restrict__ mha) {
  const int bid = blockIdx.x;
  const int bh = (bid & 7) * 4 + ((bid >> 3) >> 4);  // 4 bh per XCD (L2 locality)
  const int qt = (bid >> 3) & 15;
  const int b = bh >> 4, h = bh & 15;
  const int tid = threadIdx.x;
  const int w = tid >> 6, l = tid & 63;
  const int lr = l & 15, lq = l >> 4, l7 = lr & 7;

  __shared__ __align__(16) unsigned short Ks[2][64 * 64];  // swizzled [key][dh]
  __shared__ __align__(16) unsigned short Vt[2][64 * 64];  // swizzled [dh][kappa]
  __shared__ __align__(16) unsigned short Ps[8][16][72];   // per-wave P, padded

  const size_t bho = (size_t)bh * 131072;
  const int q0 = qt * 128 + w * 16;

  bf16x8 qf0, qf1;
  {
    const unsigned short* qp = q + bho + (size_t)(q0 + lr) * 64 + lq * 8;
    qf0 = *(const bf16x8*)qp;
    qf1 = *(const bf16x8*)(qp + 32);
  }

  f32x4 l_acc[4];
  f32x4 o[4];
#pragma unroll
  for (int i = 0; i < 4; ++i) {
    l_acc[i] = (f32x4){0.f, 0.f, 0.f, 0.f};
    o[i] = (f32x4){0.f, 0.f, 0.f, 0.f};
  }

  const unsigned short* kg = ks + bho;
  const unsigned short* vg = vp + bho;
  const int srow = l >> 3, scol = (l & 7) * 8;
  const int r0 = w * 8;

  async_ld16(kg + (size_t)(r0 + srow) * 64 + scol, &Ks[0][r0 * 64]);
  async_ld16(vg + (size_t)(r0 + srow) * 2048 + scol, &Vt[0][r0 * 64]);
  __syncthreads();

  for (int kt = 0; kt < 32; ++kt) {
    const int cur = kt & 1, nxt = cur ^ 1;
    if (kt + 1 < 32) {
      const int k1 = (kt + 1) * 64;
      async_ld16(kg + (size_t)(k1 + r0 + srow) * 64 + scol, &Ks[nxt][r0 * 64]);
      async_ld16(vg + (size_t)(r0 + srow) * 2048 + k1 + scol, &Vt[nxt][r0 * 64]);
    }

    bf16x8 kf[4][2];
#pragma unroll
    for (int ct = 0; ct < 4; ++ct)
#pragma unroll
      for (int hh = 0; hh < 2; ++hh)
        kf[ct][hh] = *(const bf16x8*)&Ks[cur][(ct * 16 + lr) * 64 +
                                             (((hh << 2) | lq) ^ l7) * 8];
    f32x4 s[4];
#pragma unroll
    for (int ct = 0; ct < 4; ++ct) {
      f32x4 t = {0.f, 0.f, 0.f, 0.f};
      t = mfma16x16x32(qf0, kf[ct][0], t);
      t = mfma16x16x32(qf1, kf[ct][1], t);
      s[ct] = t;
    }

#pragma unroll
    for (int r = 0; r < 4; ++r) {
      f32x4 pe;
#pragma unroll
      for (int ct = 0; ct < 4; ++ct)
        pe[ct] = __builtin_amdgcn_exp2f(s[ct][r]);
      l_acc[r] += pe;
      u16x4 pk;
#pragma unroll
      for (int ct = 0; ct < 4; ++ct) pk[ct] = f2bfh(pe[ct]);
      *(u16x4*)&Ps[w][lq * 4 + r][lr * 4] = pk;  // kappa = lr*4+ct
    }
    __asm__ volatile("" ::: "memory");

    bf16x8 vf[4][2];
#pragma unroll
    for (int dt = 0; dt < 4; ++dt)
#pragma unroll
      for (int hh = 0; hh < 2; ++hh)
        vf[dt][hh] = *(const bf16x8*)&Vt[cur][(dt * 16 + lr) * 64 +
                                             (((hh << 2) | lq) ^ l7) * 8];
    bf16x8 pf0 = *(const bf16x8*)&Ps[w][lr][lq * 8];
    bf16x8 pf1 = *(const bf16x8*)&Ps[w][lr][32 + lq * 8];
#pragma unroll
    for (int dt = 0; dt < 4; ++dt) {
      o[dt] = mfma16x16x32(pf0, vf[dt][0], o[dt]);
      o[dt] = mfma16x16x32(pf1, vf[dt][1], o[dt]);
    }
    __syncthreads();
  }

#pragma unroll
  for (int r = 0; r < 4; ++r) {
    f32x4 la = l_acc[r];
    float sd = la[0] + la[1] + la[2] + la[3];
    sd += __shfl_xor(sd, 1);
    sd += __shfl_xor(sd, 2);
    sd += __shfl_xor(sd, 4);
    sd += __shfl_xor(sd, 8);
    const float inv = 1.f / sd;
    float* op = mha + ((size_t)b * 2048 + q0 + lq * 4 + r) * 1024 + h * 64 + lr;
    op[0] = o[0][r] * inv;
    op[16] = o[1][r] * inv;
    op[32] = o[2][r] * inv;
    op[48] = o[3][r] * inv;
  }
}

// ---------------- fused residual-add + LayerNorm -> bf16 ----------------
__global__ __launch_bounds__(256) void k_add_ln(const float* __restrict__ a,
                                                const float* __restrict__ b,
                                                const float* __restrict__ g,
                                                const float* __restrict__ be,
                                                unsigned short* __restrict__ outb) {
  const int row = blockIdx.x;
  const int tid = threadIdx.x;
  const size_t base = (size_t)row * 1024 + tid * 4;
  f32x4 va = *(const f32x4*)(a + base);
  f32x4 vb = *(const f32x4*)(b + base);
  f32x4 xx;
  float s = 0.f, q = 0.f;
#pragma unroll
  for (int i = 0; i < 4; ++i) {
    xx[i] = va[i] + vb[i];
    s += xx[i];
    q += xx[i] * xx[i];
  }
#pragma unroll
  for (int off = 1; off < 64; off <<= 1) {
    s += __shfl_xor(s, off);
    q += __shfl_xor(q, off);
  }
  __shared__ float ss[4], qs[4];
  const int w = tid >> 6;
  if ((tid & 63) == 0) { ss[w] = s; qs[w] = q; }
  __syncthreads();
  s = ss[0] + ss[1] + ss[2] + ss[3];
  q = qs[0] + qs[1] + qs[2] + qs[3];
  const float mean = s * (1.f / 1024.f);
  const float var = q * (1.f / 1024.f) - mean * mean;
  const float rstd = rsqrtf(var + 1e-5f);
  f32x4 vg = *(const f32x4*)(g + tid * 4);
  f32x4 vbe = *(const f32x4*)(be + tid * 4);
  u16x4 pk;
#pragma unroll
  for (int i = 0; i < 4; ++i)
    pk[i] = f2bf((xx[i] - mean) * rstd * vg[i] + vbe[i]);
  *(u16x4*)(outb + base) = pk;
}

// out = LN(h1b + p0..p3 + b2): ffn2 split-K=4 partials + bias + LN (fp32 out).
__global__ __launch_bounds__(256) void k_add_ln4(
    const unsigned short* __restrict__ h1b, const unsigned short* __restrict__ pb,
    const float* __restrict__ cb, const float* __restrict__ g,
    const float* __restrict__ be, float* __restrict__ out) {
  const int row = blockIdx.x;
  const int tid = threadIdx.x;
  const size_t base = (size_t)row * 1024 + tid * 4;
  u16x4 uh = *(const u16x4*)(h1b + base);
  u16x4 up[4];
#pragma unroll
  for (int z = 0; z < 4; ++z)
    up[z] = *(const u16x4*)(pb + base + (size_t)z * 4194304);
  f32x4 vcb = *(const f32x4*)(cb + tid * 4);
  f32x4 xx;
  float s = 0.f, q = 0.f;
#pragma unroll
  for (int i = 0; i < 4; ++i) {
    float v = bf2f(uh[i]) + vcb[i];
#pragma unroll
    for (int z = 0; z < 4; ++z) v += bf2f(up[z][i]);
    xx[i] = v;
    s += v;
    q += v * v;
  }
#pragma unroll
  for (int off = 1; off < 64; off <<= 1) {
    s += __shfl_xor(s, off);
    q += __shfl_xor(q, off);
  }
  __shared__ float ss[4], qs[4];
  const int w = tid >> 6;
  if ((tid & 63) == 0) { ss[w] = s; qs[w] = q; }
  __syncthreads();
  s = ss[0] + ss[1] + ss[2] + ss[3];
  q = qs[0] + qs[1] + qs[2] + qs[3];
  const float mean = s * (1.f / 1024.f);
  const float var = q * (1.f / 1024.f) - mean * mean;
  const float rstd = rsqrtf(var + 1e-5f);
  f32x4 vg = *(const f32x4*)(g + tid * 4);
  f32x4 vbe = *(const f32x4*)(be + tid * 4);
  f32x4 ov;
#pragma unroll
  for (int i = 0; i < 4; ++i) ov[i] = (xx[i] - mean) * rstd * vg[i] + vbe[i];
  *(f32x4*)(out + base) = ov;
}

// ---------------- host launcher ----------------
extern "C" void kernel_launch(void* const* d_in, const int* in_sizes, int n_in,
                              void* d_out, int out_size, void* d_ws,
                              size_t ws_size, hipStream_t stream) {
  const float* x = (const float*)d_in[0];
  // d_in[1] attention_mask: discarded by reference (typo bug) -> unused
  const float* Wq = (const float*)d_in[2];
  const float* bq = (const float*)d_in[3];
  const float* Wk = (const float*)d_in[4];
  const float* bk = (const float*)d_in[5];
  const float* Wv = (const float*)d_in[6];
  const float* bv = (const float*)d_in[7];
  const float* lg = (const float*)d_in[8];
  const float* lb = (const float*)d_in[9];
  const float* W1 = (const float*)d_in[10];
  const float* b1 = (const float*)d_in[11];
  const float* W2 = (const float*)d_in[12];
  const float* b2 = (const float*)d_in[13];

  char* ws = (char*)d_ws;
  const size_t MB = 1024 * 1024;
  // liveness-overlapped plan (peak 94 MB):
  unsigned short* qb = (unsigned short*)(ws + 0);          // 8MB [qkv -> attn]
  unsigned short* kb = (unsigned short*)(ws + 8 * MB);     // 8MB [qkv -> attn]
  unsigned short* vb = (unsigned short*)(ws + 16 * MB);    // 8MB [qkv -> vprep]
  unsigned short* vp = (unsigned short*)(ws + 24 * MB);    // 8MB [vprep -> attn]
  unsigned short* f1 = (unsigned short*)(ws + 0);          // 32MB [ffn1 -> ffn2]
  unsigned short* xb = (unsigned short*)(ws + 32 * MB);    // 8MB [cvt -> qkv]
  unsigned short* pb = (unsigned short*)(ws + 32 * MB);    // 32MB p0..p3 [ffn2 -> ln4]
  float* mha = (float*)(ws + 40 * MB);                     // 16MB [attn -> ln1]
  unsigned short* h1b = (unsigned short*)(ws + 64 * MB);   // 8MB [ln1 -> ffn1,ln4]
  unsigned short* wqkvt = (unsigned short*)(ws + 72 * MB); // 6MB [prep -> qkv]
  unsigned short* w1t = (unsigned short*)(ws + 78 * MB);   // 8MB [prep -> ffn1]
  unsigned short* w2t = (unsigned short*)(ws + 86 * MB);   // 8MB [prep -> ffn2]

  k_cvt<<<dim3(4096), 256, 0, stream>>>(x, xb);
  k_twall<<<dim3(2816), 256, 0, stream>>>(Wq, Wk, Wv, W1, W2, wqkvt, w1t, w2t);

  k_gemm_qkv<<<dim3(32, 24), 256, 0, stream>>>(xb, wqkvt, bq, bk, bv, qb, kb, vb);
  k_vprep<<<dim3(32, 32), 256, 0, stream>>>(vb, vp);
  k_attn<<<dim3(512), 512, 0, stream>>>(qb, kb, vp, mha);
  k_add_ln<<<dim3(4096), 256, 0, stream>>>(x, mha, lg, lb, h1b);
  k_ffn1<<<dim3(32, 32), 256, 0, stream>>>(h1b, w1t, b1, f1);
  k_ffn2<<<dim3(32, 8, 4), 256, 0, stream>>>(f1, w2t, pb);
  k_add_ln4<<<dim3(4096), 256, 0, stream>>>(h1b, pb, b2, lg, lb, (float*)d_out);
}

// Round 9
// 322.896 us; speedup vs baseline: 1.0343x; 1.0343x over previous
//
#include <hip/hip_runtime.h>

#define DEVI __device__ __forceinline__

typedef __attribute__((ext_vector_type(8))) __bf16 bf16x8;
typedef __attribute__((ext_vector_type(4))) float f32x4;
typedef __attribute__((ext_vector_type(4))) unsigned short u16x4;
typedef __attribute__((ext_vector_type(8))) unsigned short u16x8;

static DEVI unsigned short f2bf(float f) {  // manual RNE (cold paths)
  unsigned int i = __float_as_uint(f);
  i += 0x7fffu + ((i >> 16) & 1u);
  return (unsigned short)(i >> 16);
}

static DEVI unsigned short f2bfh(float f) {  // native cvt
  union { __bf16 h; unsigned short u; } c;
  c.h = (__bf16)f;
  return c.u;
}

static DEVI float bf2f(unsigned short u) {
  return __uint_as_float((unsigned int)u << 16);
}

static DEVI f32x4 mfma16x16x32(bf16x8 a, bf16x8 b, f32x4 c) {
  return __builtin_amdgcn_mfma_f32_16x16x32_bf16(a, b, c, 0, 0, 0);
}

static DEVI void async_ld16(const void* g, void* lds) {
  __builtin_amdgcn_global_load_lds(
      (const __attribute__((address_space(1))) void*)g,
      (__attribute__((address_space(3))) void*)lds, 16, 0, 0);
}

// ---------------- m97-style BK=32 GEMM core (R6-proven config) ------------
// R7 post-mortem: BK=64 double-half regressed (VALUBusy 13->33%, LDS 32KB cut
// co-residency). BK=32 / 16KB LDS / 68-80 VGPR is the measured optimum for
// this 2-barrier structure — do not widen BK again.
// OUT_MODE: 0 fp32+bias; 1 bf16+bias(+RELU); 2 QKV scatter (K scaled+swizzled,
//           Q plain, V directly in attn's kappa+XOR layout); 3 bf16 raw.
template <int BN, int OUT_MODE, bool RELU>
static DEVI void gemm_bt_core(const unsigned short* __restrict__ A, int lda,
                              const unsigned short* __restrict__ Bt, int ldb,
                              int K, int m0, int n0,
                              const float* __restrict__ bias,
                              void* __restrict__ Cp, int ldc,
                              const float* __restrict__ bq,
                              const float* __restrict__ bk,
                              const float* __restrict__ bv,
                              unsigned short* __restrict__ qo,
                              unsigned short* __restrict__ ko,
                              unsigned short* __restrict__ vo) {
  constexpr int MT = (BN == 128) ? 4 : 2;
  constexpr int NT = 4;
  __shared__ __align__(16) unsigned short As[128 * 32];
  __shared__ __align__(16) unsigned short Bs[BN * 32];

  const int tid = threadIdx.x;
  const int w = tid >> 6, l = tid & 63;
  const int lr = l & 15, lq = l >> 4;
  const int wm0 = (BN == 128) ? ((w >> 1) * 64) : (w * 32);
  const int wn0 = (BN == 128) ? ((w & 1) * 64) : 0;
  const int lrow = l >> 2;
  const int lcol = (l & 3) * 8;

  f32x4 acc[MT][NT];
#pragma unroll
  for (int i = 0; i < MT; ++i)
#pragma unroll
    for (int j = 0; j < NT; ++j) acc[i][j] = (f32x4){0.f, 0.f, 0.f, 0.f};

  for (int kb = 0; kb < K; kb += 32) {
#pragma unroll
    for (int p = 0; p < 2; ++p) {
      const int r0 = p * 64 + w * 16;
      async_ld16(A + (size_t)(m0 + r0 + lrow) * lda + kb + lcol, As + r0 * 32);
    }
#pragma unroll
    for (int p = 0; p < BN / 64; ++p) {
      const int r0 = p * 64 + w * 16;
      async_ld16(Bt + (size_t)(n0 + r0 + lrow) * ldb + kb + lcol, Bs + r0 * 32);
    }
    __syncthreads();

    bf16x8 af[MT], bfr[NT];
#pragma unroll
    for (int mt = 0; mt < MT; ++mt)
      af[mt] = *(const bf16x8*)(As + (wm0 + mt * 16 + lr) * 32 + lq * 8);
#pragma unroll
    for (int nt = 0; nt < NT; ++nt)
      bfr[nt] = *(const bf16x8*)(Bs + (wn0 + nt * 16 + lr) * 32 + lq * 8);
#pragma unroll
    for (int mt = 0; mt < MT; ++mt)
#pragma unroll
      for (int nt = 0; nt < NT; ++nt)
        acc[mt][nt] = mfma16x16x32(af[mt], bfr[nt], acc[mt][nt]);
    __syncthreads();
  }

#pragma unroll
  for (int mt = 0; mt < MT; ++mt) {
    const int grow = m0 + wm0 + mt * 16 + lq * 4;
#pragma unroll
    for (int nt = 0; nt < NT; ++nt) {
      const int gcol = n0 + wn0 + nt * 16 + lr;
      if (OUT_MODE == 2) {
        const int which = gcol >> 10;
        const int h = (gcol >> 6) & 15;
        const int e = gcol & 63;
        const float* bp = (which == 0) ? bq : (which == 1) ? bk : bv;
        const float bvv = bp[gcol & 1023];
#pragma unroll
        for (int r = 0; r < 4; ++r) {
          const int row = grow + r;
          const int b_ = row >> 11, s_ = row & 2047;
          const size_t base = (size_t)((b_ << 4) + h) * 131072;
          const float val = acc[mt][nt][r] + bvv;
          if (which == 0) {
            qo[base + (size_t)s_ * 64 + e] = f2bf(val);
          } else if (which == 1) {
            // K: fold softmax scale (1/8 * log2e) + XOR-octet swizzle for
            // conflict-free unpadded LDS reads in k_attn.
            const int o = e >> 3;
            const int pos = (((o ^ (s_ & 7)) << 3) | (e & 7));
            ko[base + (size_t)s_ * 64 + pos] = f2bf(val * 0.18033688011112f);
          } else {
            // V: directly into attn layout [dh][2048], kappa-permuted +
            // XOR-octet swizzled per 64-key tile (formulas R5-verified).
            const int t = s_ >> 6, k64 = s_ & 63;
            const int kap = (k64 & 15) * 4 + (k64 >> 4);
            const int pos = (((kap >> 3) ^ (e & 7)) << 3) | (kap & 7);
            vo[base + (size_t)e * 2048 + t * 64 + pos] = f2bf(val);
          }
        }
      } else if (OUT_MODE == 3) {
#pragma unroll
        for (int r = 0; r < 4; ++r)
          ((unsigned short*)Cp)[(size_t)(grow + r) * ldc + gcol] =
              f2bf(acc[mt][nt][r]);
      } else {
        const float bvv = bias[gcol];
#pragma unroll
        for (int r = 0; r < 4; ++r) {
          float val = acc[mt][nt][r] + bvv;
          if (RELU) val = fmaxf(val, 0.f);
          if (OUT_MODE == 1)
            ((unsigned short*)Cp)[(size_t)(grow + r) * ldc + gcol] = f2bf(val);
          else
            ((float*)Cp)[(size_t)(grow + r) * ldc + gcol] = val;
        }
      }
    }
  }
}

__global__ __launch_bounds__(256) void k_gemm_qkv(
    const unsigned short* __restrict__ xb, const unsigned short* __restrict__ Wt,
    const float* __restrict__ bq, const float* __restrict__ bk,
    const float* __restrict__ bv, unsigned short* __restrict__ qo,
    unsigned short* __restrict__ ko, unsigned short* __restrict__ vo) {
  gemm_bt_core<128, 2, false>(xb, 1024, Wt, 1024, 1024, blockIdx.x * 128,
                              blockIdx.y * 128, nullptr, nullptr, 0, bq, bk, bv,
                              qo, ko, vo);
}

__global__ __launch_bounds__(256) void k_ffn1(
    const unsigned short* __restrict__ h1b, const unsigned short* __restrict__ W1t,
    const float* __restrict__ b1, unsigned short* __restrict__ f1) {
  gemm_bt_core<128, 1, true>(h1b, 1024, W1t, 1024, 1024, blockIdx.x * 128,
                             blockIdx.y * 128, b1, f1, 4096, nullptr, nullptr,
                             nullptr, nullptr, nullptr, nullptr);
}

// split-K=4, BN=128: z covers k in [z*1024, z*1024+1024); partials contiguous
// at pbase + z*4M elements. 1024 blocks -> 4 blocks/CU.
__global__ __launch_bounds__(256) void k_ffn2(
    const unsigned short* __restrict__ f1, const unsigned short* __restrict__ W2t,
    unsigned short* __restrict__ pbase) {
  const int z = blockIdx.z;
  unsigned short* p = pbase + (size_t)z * 4194304;
  gemm_bt_core<128, 3, false>(f1 + z * 1024, 4096, W2t + z * 1024, 4096, 1024,
                              blockIdx.x * 128, blockIdx.y * 128, nullptr, p,
                              1024, nullptr, nullptr, nullptr, nullptr, nullptr,
                              nullptr);
}

// ---------------- unified prep: x cvt + all weight transposes -------------
static DEVI void tr64(const float* __restrict__ s, int sld,
                      unsigned short* __restrict__ d, int dld) {
  __shared__ float t[64][65];
  const int tr = threadIdx.x >> 4;
  const int tc4 = (threadIdx.x & 15) * 4;
#pragma unroll
  for (int i = 0; i < 4; ++i) {
    f32x4 v = *(const f32x4*)(s + (size_t)(i * 16 + tr) * sld + tc4);
#pragma unroll
    for (int j = 0; j < 4; ++j) t[i * 16 + tr][tc4 + j] = v[j];
  }
  __syncthreads();
#pragma unroll
  for (int i = 0; i < 4; ++i) {
    const int c = i * 16 + tr;
    u16x4 pk;
#pragma unroll
    for (int j = 0; j < 4; ++j) pk[j] = f2bf(t[tc4 + j][c]);
    *(u16x4*)(d + (size_t)c * dld + tc4) = pk;
  }
}

// Flat grid 3840 blocks:
//   [0,1024)     x fp32 -> bf16 (16 elems/thread)
//   [1024,1792)  Wq/Wk/Wv [H][1024][64] -> wqkvt [3072][1024]
//   [1792,2816)  W1 [1024][4096]        -> w1t   [4096][1024]
//   [2816,3840)  W2 [4096][1024]        -> w2t   [1024][4096]
__global__ __launch_bounds__(256) void k_prep(
    const float* __restrict__ x, const float* __restrict__ Wq,
    const float* __restrict__ Wk, const float* __restrict__ Wv,
    const float* __restrict__ W1, const float* __restrict__ W2,
    unsigned short* __restrict__ xb, unsigned short* __restrict__ wqkvt,
    unsigned short* __restrict__ w1t, unsigned short* __restrict__ w2t) {
  const int bid = blockIdx.x;
  if (bid < 1024) {
    const size_t i0 = ((size_t)bid * 256 + threadIdx.x) * 16;
#pragma unroll
    for (int c = 0; c < 4; ++c) {
      f32x4 v = *(const f32x4*)(x + i0 + c * 4);
      u16x4 pk;
#pragma unroll
      for (int j = 0; j < 4; ++j) pk[j] = f2bf(v[j]);
      *(u16x4*)(xb + i0 + c * 4) = pk;
    }
  } else if (bid < 1792) {
    const int t = bid - 1024;
    const int bx = t & 15, by = t >> 4;  // by: 0..47
    const int which = by >> 4, h = by & 15;
    const float* W = (which == 0) ? Wq : (which == 1) ? Wk : Wv;
    const float* s = W + (size_t)h * 65536;
    unsigned short* d = wqkvt + (size_t)(which * 1024 + h * 64) * 1024;
    const int r0 = bx * 64;
    tr64(s + (size_t)r0 * 64, 64, d + r0, 1024);
  } else if (bid < 2816) {
    const int t = bid - 1792;
    const int bx = t & 15, by = t >> 4;  // R=1024, C=4096
    const int r0 = bx * 64, c0 = by * 64;
    tr64(W1 + (size_t)r0 * 4096 + c0, 4096, w1t + (size_t)c0 * 1024 + r0, 1024);
  } else {
    const int t = bid - 2816;
    const int bx = t & 63, by = t >> 6;  // R=4096, C=1024
    const int r0 = bx * 64, c0 = by * 64;
    tr64(W2 + (size_t)r0 * 1024 + c0, 1024, w2t + (size_t)c0 * 4096 + r0, 4096);
  }
}

// ---------------- flash attention (unmasked per reference bug) -------------
// No-max softmax (|score*scale| < ~4, exp2-safe). Scale pre-folded into K.
// 512 threads / 8 waves, 16 Q-rows per wave; async dbuf staging, 1 barrier.
// mha written bf16.
__global__ __launch_bounds__(512) void k_attn(
    const unsigned short* __restrict__ q, const unsigned short* __restrict__ ks,
    const unsigned short* __restrict__ vp, unsigned short* __restrict__ mha) {
  const int bid = blockIdx.x;
  const int bh = (bid & 7) * 4 + ((bid >> 3) >> 4);  // 4 bh per XCD (L2 locality)
  const int qt = (bid >> 3) & 15;
  const int b = bh >> 4, h = bh & 15;
  const int tid = threadIdx.x;
  const int w = tid >> 6, l = tid & 63;
  const int lr = l & 15, lq = l >> 4, l7 = lr & 7;

  __shared__ __align__(16) unsigned short Ks[2][64 * 64];  // swizzled [key][dh]
  __shared__ __align__(16) unsigned short Vt[2][64 * 64];  // swizzled [dh][kappa]
  __shared__ __align__(16) unsigned short Ps[8][16][72];   // per-wave P, padded

  const size_t bho = (size_t)bh * 131072;
  const int q0 = qt * 128 + w * 16;

  bf16x8 qf0, qf1;
  {
    const unsigned short* qp = q + bho + (size_t)(q0 + lr) * 64 + lq * 8;
    qf0 = *(const bf16x8*)qp;
    qf1 = *(const bf16x8*)(qp + 32);
  }

  f32x4 l_acc[4];
  f32x4 o[4];
#pragma unroll
  for (int i = 0; i < 4; ++i) {
    l_acc[i] = (f32x4){0.f, 0.f, 0.f, 0.f};
    o[i] = (f32x4){0.f, 0.f, 0.f, 0.f};
  }

  const unsigned short* kg = ks + bho;
  const unsigned short* vg = vp + bho;
  const int srow = l >> 3, scol = (l & 7) * 8;
  const int r0 = w * 8;

  async_ld16(kg + (size_t)(r0 + srow) * 64 + scol, &Ks[0][r0 * 64]);
  async_ld16(vg + (size_t)(r0 + srow) * 2048 + scol, &Vt[0][r0 * 64]);
  __syncthreads();

  for (int kt = 0; kt < 32; ++kt) {
    const int cur = kt & 1, nxt = cur ^ 1;
    if (kt + 1 < 32) {
      const int k1 = (kt + 1) * 64;
      async_ld16(kg + (size_t)(k1 + r0 + srow) * 64 + scol, &Ks[nxt][r0 * 64]);
      async_ld16(vg + (size_t)(r0 + srow) * 2048 + k1 + scol, &Vt[nxt][r0 * 64]);
    }

    bf16x8 kf[4][2];
#pragma unroll
    for (int ct = 0; ct < 4; ++ct)
#pragma unroll
      for (int hh = 0; hh < 2; ++hh)
        kf[ct][hh] = *(const bf16x8*)&Ks[cur][(ct * 16 + lr) * 64 +
                                             (((hh << 2) | lq) ^ l7) * 8];
    f32x4 s[4];
#pragma unroll
    for (int ct = 0; ct < 4; ++ct) {
      f32x4 t = {0.f, 0.f, 0.f, 0.f};
      t = mfma16x16x32(qf0, kf[ct][0], t);
      t = mfma16x16x32(qf1, kf[ct][1], t);
      s[ct] = t;
    }

#pragma unroll
    for (int r = 0; r < 4; ++r) {
      f32x4 pe;
#pragma unroll
      for (int ct = 0; ct < 4; ++ct)
        pe[ct] = __builtin_amdgcn_exp2f(s[ct][r]);
      l_acc[r] += pe;
      u16x4 pk;
#pragma unroll
      for (int ct = 0; ct < 4; ++ct) pk[ct] = f2bfh(pe[ct]);
      *(u16x4*)&Ps[w][lq * 4 + r][lr * 4] = pk;  // kappa = lr*4+ct
    }
    __asm__ volatile("" ::: "memory");

    bf16x8 vf[4][2];
#pragma unroll
    for (int dt = 0; dt < 4; ++dt)
#pragma unroll
      for (int hh = 0; hh < 2; ++hh)
        vf[dt][hh] = *(const bf16x8*)&Vt[cur][(dt * 16 + lr) * 64 +
                                             (((hh << 2) | lq) ^ l7) * 8];
    bf16x8 pf0 = *(const bf16x8*)&Ps[w][lr][lq * 8];
    bf16x8 pf1 = *(const bf16x8*)&Ps[w][lr][32 + lq * 8];
#pragma unroll
    for (int dt = 0; dt < 4; ++dt) {
      o[dt] = mfma16x16x32(pf0, vf[dt][0], o[dt]);
      o[dt] = mfma16x16x32(pf1, vf[dt][1], o[dt]);
    }
    __syncthreads();
  }

#pragma unroll
  for (int r = 0; r < 4; ++r) {
    f32x4 la = l_acc[r];
    float sd = la[0] + la[1] + la[2] + la[3];
    sd += __shfl_xor(sd, 1);
    sd += __shfl_xor(sd, 2);
    sd += __shfl_xor(sd, 4);
    sd += __shfl_xor(sd, 8);
    const float inv = 1.f / sd;
    unsigned short* op =
        mha + ((size_t)b * 2048 + q0 + lq * 4 + r) * 1024 + h * 64 + lr;
    op[0] = f2bfh(o[0][r] * inv);
    op[16] = f2bfh(o[1][r] * inv);
    op[32] = f2bfh(o[2][r] * inv);
    op[48] = f2bfh(o[3][r] * inv);
  }
}

// ---------------- fused residual-add + LayerNorm -> bf16 ----------------
// a fp32 (x), b bf16 (mha).
__global__ __launch_bounds__(256) void k_add_ln(const float* __restrict__ a,
                                                const unsigned short* __restrict__ b,
                                                const float* __restrict__ g,
                                                const float* __restrict__ be,
                                                unsigned short* __restrict__ outb) {
  const int row = blockIdx.x;
  const int tid = threadIdx.x;
  const size_t base = (size_t)row * 1024 + tid * 4;
  f32x4 va = *(const f32x4*)(a + base);
  u16x4 ub = *(const u16x4*)(b + base);
  f32x4 xx;
  float s = 0.f, q = 0.f;
#pragma unroll
  for (int i = 0; i < 4; ++i) {
    xx[i] = va[i] + bf2f(ub[i]);
    s += xx[i];
    q += xx[i] * xx[i];
  }
#pragma unroll
  for (int off = 1; off < 64; off <<= 1) {
    s += __shfl_xor(s, off);
    q += __shfl_xor(q, off);
  }
  __shared__ float ss[4], qs[4];
  const int w = tid >> 6;
  if ((tid & 63) == 0) { ss[w] = s; qs[w] = q; }
  __syncthreads();
  s = ss[0] + ss[1] + ss[2] + ss[3];
  q = qs[0] + qs[1] + qs[2] + qs[3];
  const float mean = s * (1.f / 1024.f);
  const float var = q * (1.f / 1024.f) - mean * mean;
  const float rstd = rsqrtf(var + 1e-5f);
  f32x4 vg = *(const f32x4*)(g + tid * 4);
  f32x4 vbe = *(const f32x4*)(be + tid * 4);
  u16x4 pk;
#pragma unroll
  for (int i = 0; i < 4; ++i)
    pk[i] = f2bf((xx[i] - mean) * rstd * vg[i] + vbe[i]);
  *(u16x4*)(outb + base) = pk;
}

// out = LN(h1b + p0..p3 + b2): ffn2 split-K=4 partials + bias + LN (fp32 out).
__global__ __launch_bounds__(256) void k_add_ln4(
    const unsigned short* __restrict__ h1b, const unsigned short* __restrict__ pb,
    const float* __restrict__ cb, const float* __restrict__ g,
    const float* __restrict__ be, float* __restrict__ out) {
  const int row = blockIdx.x;
  const int tid = threadIdx.x;
  const size_t base = (size_t)row * 1024 + tid * 4;
  u16x4 uh = *(const u16x4*)(h1b + base);
  u16x4 up[4];
#pragma unroll
  for (int z = 0; z < 4; ++z)
    up[z] = *(const u16x4*)(pb + base + (size_t)z * 4194304);
  f32x4 vcb = *(const f32x4*)(cb + tid * 4);
  f32x4 xx;
  float s = 0.f, q = 0.f;
#pragma unroll
  for (int i = 0; i < 4; ++i) {
    float v = bf2f(uh[i]) + vcb[i];
#pragma unroll
    for (int z = 0; z < 4; ++z) v += bf2f(up[z][i]);
    xx[i] = v;
    s += v;
    q += v * v;
  }
#pragma unroll
  for (int off = 1; off < 64; off <<= 1) {
    s += __shfl_xor(s, off);
    q += __shfl_xor(q, off);
  }
  __shared__ float ss[4], qs[4];
  const int w = tid >> 6;
  if ((tid & 63) == 0) { ss[w] = s; qs[w] = q; }
  __syncthreads();
  s = ss[0] + ss[1] + ss[2] + ss[3];
  q = qs[0] + qs[1] + qs[2] + qs[3];
  const float mean = s * (1.f / 1024.f);
  const float var = q * (1.f / 1024.f) - mean * mean;
  const float rstd = rsqrtf(var + 1e-5f);
  f32x4 vg = *(const f32x4*)(g + tid * 4);
  f32x4 vbe = *(const f32x4*)(be + tid * 4);
  f32x4 ov;
#pragma unroll
  for (int i = 0; i < 4; ++i) ov[i] = (xx[i] - mean) * rstd * vg[i] + vbe[i];
  *(f32x4*)(out + base) = ov;
}

// ---------------- host launcher ----------------
extern "C" void kernel_launch(void* const* d_in, const int* in_sizes, int n_in,
                              void* d_out, int out_size, void* d_ws,
                              size_t ws_size, hipStream_t stream) {
  const float* x = (const float*)d_in[0];
  // d_in[1] attention_mask: discarded by reference (typo bug) -> unused
  const float* Wq = (const float*)d_in[2];
  const float* bq = (const float*)d_in[3];
  const float* Wk = (const float*)d_in[4];
  const float* bk = (const float*)d_in[5];
  const float* Wv = (const float*)d_in[6];
  const float* bv = (const float*)d_in[7];
  const float* lg = (const float*)d_in[8];
  const float* lb = (const float*)d_in[9];
  const float* W1 = (const float*)d_in[10];
  const float* b1 = (const float*)d_in[11];
  const float* W2 = (const float*)d_in[12];
  const float* b2 = (const float*)d_in[13];

  char* ws = (char*)d_ws;
  const size_t MB = 1024 * 1024;
  // liveness-overlapped plan (peak 94 MB):
  unsigned short* qb = (unsigned short*)(ws + 0);          // 8MB [qkv -> attn]
  unsigned short* kb = (unsigned short*)(ws + 8 * MB);     // 8MB [qkv -> attn]
  unsigned short* vp = (unsigned short*)(ws + 16 * MB);    // 8MB [qkv -> attn]
  unsigned short* f1 = (unsigned short*)(ws + 0);          // 32MB [ffn1 -> ffn2]
  unsigned short* xb = (unsigned short*)(ws + 32 * MB);    // 8MB [prep -> qkv]
  unsigned short* pb = (unsigned short*)(ws + 32 * MB);    // 32MB [ffn2 -> ln4]
  unsigned short* mha = (unsigned short*)(ws + 40 * MB);   // 8MB bf16 [attn -> ln1]
  unsigned short* h1b = (unsigned short*)(ws + 64 * MB);   // 8MB [ln1 -> ffn1,ln4]
  unsigned short* wqkvt = (unsigned short*)(ws + 72 * MB); // 6MB [prep -> qkv]
  unsigned short* w1t = (unsigned short*)(ws + 78 * MB);   // 8MB [prep -> ffn1]
  unsigned short* w2t = (unsigned short*)(ws + 86 * MB);   // 8MB [prep -> ffn2]

  k_prep<<<dim3(3840), 256, 0, stream>>>(x, Wq, Wk, Wv, W1, W2, xb, wqkvt, w1t,
                                         w2t);
  k_gemm_qkv<<<dim3(32, 24), 256, 0, stream>>>(xb, wqkvt, bq, bk, bv, qb, kb, vp);
  k_attn<<<dim3(512), 512, 0, stream>>>(qb, kb, vp, mha);
  k_add_ln<<<dim3(4096), 256, 0, stream>>>(x, mha, lg, lb, h1b);
  k_ffn1<<<dim3(32, 32), 256, 0, stream>>>(h1b, w1t, b1, f1);
  k_ffn2<<<dim3(32, 8, 4), 256, 0, stream>>>(f1, w2t, pb);
  k_add_ln4<<<dim3(4096), 256, 0, stream>>>(h1b, pb, b2, lg, lb, (float*)d_out);
}